// Round 1
// baseline (208.614 us; speedup 1.0000x reference)
//
#include <hip/hip_runtime.h>

#define FEAT 128

// One 64-lane wave per segment.
// Lane l reads float4 at feature offset 4*(l&31) of row (l>>5)+2*t.
// Per iteration the wave reads a contiguous 1024B chunk (2 rows).
__global__ __launch_bounds__(256) void jagged_max_kernel(
    const float* __restrict__ values,
    const int* __restrict__ prefix,
    float* __restrict__ out,
    int n_seg)
{
    const int gwave = (blockIdx.x * blockDim.x + threadIdx.x) >> 6;  // global wave id = segment id
    const int lane  = threadIdx.x & 63;
    if (gwave >= n_seg) return;

    const int s     = gwave;
    const int start = (s == 0) ? 0 : prefix[s - 1];
    const int end   = prefix[s];
    const int len   = end - start;

    const int half = lane >> 5;   // 0: even rows, 1: odd rows
    const int q    = lane & 31;   // which float4 of the 128-feature row

    float4 m = make_float4(-INFINITY, -INFINITY, -INFINITY, -INFINITY);

    const float* base = values + (size_t)start * FEAT + 4 * q;
    for (int r = half; r < len; r += 2) {
        const float4 v = *reinterpret_cast<const float4*>(base + (size_t)r * FEAT);
        m.x = fmaxf(m.x, v.x);
        m.y = fmaxf(m.y, v.y);
        m.z = fmaxf(m.z, v.z);
        m.w = fmaxf(m.w, v.w);
    }

    // Combine the two halves of the wave (row-parity partials).
    float4 o;
    o.x = __shfl_xor(m.x, 32);
    o.y = __shfl_xor(m.y, 32);
    o.z = __shfl_xor(m.z, 32);
    o.w = __shfl_xor(m.w, 32);

    if (half == 0) {
        m.x = fmaxf(m.x, o.x);
        m.y = fmaxf(m.y, o.y);
        m.z = fmaxf(m.z, o.z);
        m.w = fmaxf(m.w, o.w);
        *reinterpret_cast<float4*>(out + (size_t)s * FEAT + 4 * q) = m;
    }
}

extern "C" void kernel_launch(void* const* d_in, const int* in_sizes, int n_in,
                              void* d_out, int out_size, void* d_ws, size_t ws_size,
                              hipStream_t stream) {
    const float* values = (const float*)d_in[0];
    const int*   prefix = (const int*)d_in[1];
    float*       out    = (float*)d_out;

    const int n_seg = in_sizes[1];

    const int threads = 256;                    // 4 waves -> 4 segments per block
    const int waves_per_block = threads / 64;
    const int blocks = (n_seg + waves_per_block - 1) / waves_per_block;

    jagged_max_kernel<<<blocks, threads, 0, stream>>>(values, prefix, out, n_seg);
}

// Round 3
// 183.982 us; speedup vs baseline: 1.1339x; 1.1339x over previous
//
#include <hip/hip_runtime.h>

#define FEAT 128

typedef float f32x4 __attribute__((ext_vector_type(4)));

__device__ __forceinline__ f32x4 fmax4(f32x4 a, f32x4 b) {
    f32x4 r;
    r.x = fmaxf(a.x, b.x);
    r.y = fmaxf(a.y, b.y);
    r.z = fmaxf(a.z, b.z);
    r.w = fmaxf(a.w, b.w);
    return r;
}

// One 64-lane wave per segment.
// Lanes 0-31 handle even rows, lanes 32-63 odd rows; each lane owns one
// f32x4 (16B) column of the 128-float row. Every wave iteration reads a
// contiguous 1024B chunk (2 rows). 2x unrolled -> 2 loads in flight/lane.
__global__ __launch_bounds__(256) void jagged_max_kernel(
    const float* __restrict__ values,
    const int* __restrict__ prefix,
    float* __restrict__ out,
    int n_seg)
{
    const int gwave = (blockIdx.x * blockDim.x + threadIdx.x) >> 6;
    const int lane  = threadIdx.x & 63;
    if (gwave >= n_seg) return;

    const int s     = gwave;
    const int start = (s == 0) ? 0 : prefix[s - 1];
    const int len   = prefix[s] - start;

    const int half = lane >> 5;   // row parity this lane covers
    const int q    = lane & 31;   // which f32x4 of the row

    // base points at this lane's f32x4 column of row 0; row stride = 32 f32x4s
    const f32x4* base =
        reinterpret_cast<const f32x4*>(values + (size_t)start * FEAT) + q;

    f32x4 m0 = {-INFINITY, -INFINITY, -INFINITY, -INFINITY};
    f32x4 m1 = m0;

    int r = half;
    for (; r + 2 < len; r += 4) {
        const f32x4 a = __builtin_nontemporal_load(base + (size_t)r * 32);
        const f32x4 b = __builtin_nontemporal_load(base + (size_t)(r + 2) * 32);
        m0 = fmax4(m0, a);
        m1 = fmax4(m1, b);
    }
    if (r < len) {
        const f32x4 a = __builtin_nontemporal_load(base + (size_t)r * 32);
        m0 = fmax4(m0, a);
    }
    m0 = fmax4(m0, m1);

    // Combine the two row-parity halves of the wave.
    f32x4 o;
    o.x = __shfl_xor(m0.x, 32);
    o.y = __shfl_xor(m0.y, 32);
    o.z = __shfl_xor(m0.z, 32);
    o.w = __shfl_xor(m0.w, 32);
    m0 = fmax4(m0, o);

    if (half == 0) {
        __builtin_nontemporal_store(
            m0, reinterpret_cast<f32x4*>(out + (size_t)s * FEAT) + q);
    }
}

extern "C" void kernel_launch(void* const* d_in, const int* in_sizes, int n_in,
                              void* d_out, int out_size, void* d_ws, size_t ws_size,
                              hipStream_t stream) {
    const float* values = (const float*)d_in[0];
    const int*   prefix = (const int*)d_in[1];
    float*       out    = (float*)d_out;

    const int n_seg = in_sizes[1];

    const int threads = 256;                 // 4 waves -> 4 segments per block
    const int waves_per_block = threads / 64;
    const int blocks = (n_seg + waves_per_block - 1) / waves_per_block;

    jagged_max_kernel<<<blocks, threads, 0, stream>>>(values, prefix, out, n_seg);
}